// Round 10
// baseline (366.324 us; speedup 1.0000x reference)
//
#include <hip/hip_runtime.h>
#include <math.h>

#define N_NODES 661
#define N_GRAPH 128
#define DEG 8
#define EPG (N_NODES*DEG)          // 5288 edges per graph per matrix
#define NTOT (N_NODES*N_GRAPH)     // 84608 nodes
#define FDIM 64
#define NF ((size_t)NTOT*FDIM)     // elements per [n,64] array
#define OSTR 672                   // padded CSR offsets stride
#define PSTR 7296                  // padded pairs stride (>= 5288 + 3*661 = 7271)
#define PPAD 7272                  // LDS padded pair capacity
#define NTILE 11
#define TROWS 61                   // 11*61 = 671 >= 661
#define PACKB 1024                 // pack blocks in prep_pack

using short8  = __attribute__((ext_vector_type(8))) short;
using float4v = __attribute__((ext_vector_type(4))) float;

__device__ __forceinline__ unsigned short f2bf(float x) {
    unsigned int u = __float_as_uint(x);
    unsigned int r = u + 0x7FFFu + ((u >> 16) & 1u);
    return (unsigned short)(r >> 16);
}
__device__ __forceinline__ float bf2f(unsigned short h) {
    return __uint_as_float(((unsigned int)h) << 16);
}
// pack float into (bf16_hi << 16) | bf16_lo residual
__device__ __forceinline__ unsigned pack_bf(float x) {
    unsigned short h = f2bf(x);
    unsigned short l = f2bf(x - bf2f(h));
    return ((unsigned)h << 16) | (unsigned)l;
}

// ---------------------------------------------------------------------------
// Kernel 0: prep_pack — LDS-FREE streaming kernel. blocks 0..79: wtrans
// (bf16 hi/lo W fragments in MFMA B-layout). blocks 80..: pack ef into
// (bf16(e)<<16)|bf16(f) words for the gather kernel.
// ---------------------------------------------------------------------------
__global__ __launch_bounds__(256) void prep_pack(
    const float* __restrict__ W1, const float* __restrict__ W2,
    const float* __restrict__ e, const float* __restrict__ f,
    unsigned short* __restrict__ Wb1h, unsigned short* __restrict__ Wb1l,
    unsigned short* __restrict__ Wb2h, unsigned short* __restrict__ Wb2l,
    unsigned* __restrict__ efh)
{
    int bid = blockIdx.x;
    int tid = threadIdx.x;

    if (bid < 80) {                       // ---- wtrans part ----
        int i = bid*256 + tid;            // 0..20479
        int j    = i & 7;
        int lane = (i >> 3) & 63;
        int ot   = (i >> 9) & 3;
        int ks   = i >> 11;
        int k = ks*32 + (lane >> 4)*8 + j;
        int o = ot*16 + (lane & 15);
        float w1 = W1[o*320 + k];
        float w2 = W2[o*320 + k];
        unsigned short h1 = f2bf(w1); Wb1h[i] = h1; Wb1l[i] = f2bf(w1 - bf2f(h1));
        unsigned short h2 = f2bf(w2); Wb2h[i] = h2; Wb2l[i] = f2bf(w2 - bf2f(h2));
        return;
    }

    // ---- ef bf16-pair pack ----
    const int nf4 = (int)(NF/4);
    int i0 = (bid - 80)*256 + tid;
    const int stride = PACKB*256;
    const float4v* e4 = (const float4v*)e;
    const float4v* f4 = (const float4v*)f;
    uint4* o4 = (uint4*)efh;
    for (int i = i0; i < nf4; i += stride) {
        float4v ev = e4[i];
        float4v fv = f4[i];
        uint4 u;
        u.x = ((unsigned)f2bf(ev[0]) << 16) | (unsigned)f2bf(fv[0]);
        u.y = ((unsigned)f2bf(ev[1]) << 16) | (unsigned)f2bf(fv[1]);
        u.z = ((unsigned)f2bf(ev[2]) << 16) | (unsigned)f2bf(fv[2]);
        u.w = ((unsigned)f2bf(ev[3]) << 16) | (unsigned)f2bf(fv[3]);
        o4[i] = u;
    }
}

// ---------------------------------------------------------------------------
// Kernel 1: csr_build v3 (R9 proven) — 1024 threads + PADDED rows (multiple
// of 4 slots, col=gbase/val=0) so the gather inner loop is predicate-free.
// ---------------------------------------------------------------------------
__global__ __launch_bounds__(1024) void csr_build(
    const int* __restrict__ rG, const int* __restrict__ cG, const float* __restrict__ vG,
    const int* __restrict__ rB, const int* __restrict__ cB, const float* __restrict__ vB,
    const int* __restrict__ r1, const int* __restrict__ c1, const float* __restrict__ v1,
    const int* __restrict__ r2, const int* __restrict__ c2, const float* __restrict__ v2,
    int* __restrict__ offs_out, int2* __restrict__ pairs_out)
{
    __shared__ int   scount[N_NODES];
    __shared__ int   soffs[N_NODES+1];
    __shared__ int   scursor[N_NODES];
    __shared__ int   scol[PPAD];
    __shared__ float sval[PPAD];
    __shared__ int   swsum[16];
    __shared__ int   swoff[16];
    __shared__ int   stot;

    int bid = blockIdx.x;
    int tid = threadIdx.x;
    int lane = tid & 63, w = tid >> 6;
    int g = bid & 127;
    int m = bid >> 7;
    const int*   rows = (m==0)?rG:(m==1)?rB:(m==2)?r1:r2;
    const int*   cols = (m==0)?cG:(m==1)?cB:(m==2)?c1:c2;
    const float* vals = (m==0)?vG:(m==1)?vB:(m==2)?v1:v2;

    int ebase = g*EPG;
    int gbase = g*N_NODES;
    int seg = m*N_GRAPH + g;

    if (tid < N_NODES) scount[tid] = 0;
    __syncthreads();
    for (int i = tid; i < EPG; i += 1024)
        atomicAdd(&scount[rows[ebase+i] - gbase], 1);
    __syncthreads();

    // two-level exclusive scan over PADDED counts
    int cnt  = (tid < N_NODES) ? scount[tid] : 0;
    int pcnt = (cnt + 3) & ~3;
    int v = pcnt;
    #pragma unroll
    for (int d = 1; d < 64; d <<= 1) {
        int t = __shfl_up(v, (unsigned)d, 64);
        if (lane >= d) v += t;
    }
    if (lane == 63) swsum[w] = v;
    __syncthreads();
    if (w == 0 && lane < 16) {
        int s = swsum[lane];
        #pragma unroll
        for (int d = 1; d < 16; d <<= 1) {
            int t = __shfl_up(s, (unsigned)d, 16);
            if ((lane & 15) >= d) s += t;
        }
        swoff[lane] = s - swsum[lane];     // exclusive wave offset
        if (lane == 15) stot = s;          // padded total
    }
    __syncthreads();
    int excl = v - pcnt + swoff[w];
    if (tid < N_NODES) { soffs[tid] = excl; scursor[tid] = excl; }
    if (tid == 0) soffs[N_NODES] = stot;
    __syncthreads();

    // placement of real pairs + pad-slot fill (disjoint indices, no race)
    for (int i = tid; i < EPG; i += 1024) {
        int r = rows[ebase+i] - gbase;
        int pos = atomicAdd(&scursor[r], 1);
        scol[pos] = cols[ebase+i];
        sval[pos] = vals[ebase+i];
    }
    for (int i = tid; i < N_NODES; i += 1024) {
        int d = scount[i];
        int s0 = soffs[i] + d, e0 = soffs[i] + ((d + 3) & ~3);
        for (int k = s0; k < e0; ++k) { scol[k] = gbase; sval[k] = 0.f; }
    }
    __syncthreads();

    int total = soffs[N_NODES];
    if (tid <= N_NODES) offs_out[(size_t)seg*OSTR + tid] = soffs[tid];
    int2* po = pairs_out + (size_t)seg*PSTR;
    for (int i = tid; i < total; i += 1024)
        po[i] = make_int2(scol[i], __float_as_int(sval[i]));
}

// ---------------------------------------------------------------------------
__device__ __forceinline__ void node_math1(
    float ev, float fv, float gd, float bd, float pd, float qd,
    float eGv, float fGv, float eBv, float fBv,
    float& e3v, float& nev, float& f3v, float& nfv)
{
    float invb = 1.0f/(ev*ev + fv*fv + 0.1f);
    float alpha = (pd*ev + qd*fv)*invb - eGv - fBv;
    float beta  = (qd*ev - pd*fv)*invb + fGv + eBv;
    float invg = 1.0f/(gd*gd + bd*bd);
    e3v = (alpha*gd + beta*bd)*invg;
    f3v = (beta*gd - alpha*bd)*invg;
    float bb1 = eGv - fBv, bb2 = fGv + eBv;
    float vv = ev*ev + fv*fv;
    float P_ = pd - vv*gd, Q_ = qd + vv*bd;
    nev = (P_*bb1 + Q_*bb2)*invg;
    nfv = (P_*bb2 - Q_*bb1)*invg;
}

// ---------------------------------------------------------------------------
// Kernel 2: gather SpMM v9 — padded CSR (R9) + SOFTWARE PIPELINING:
// (a) next row's 4 CSR offsets issued at the top of the current iteration,
//     consumed next iteration (rotation) — offset latency off critical path;
// (b) pairs double-buffered: chunk k+1's pair loads issue between chunk k's
//     gathers and FMAs — pair latency hidden under gather latency.
// Zero per-slot predication; wave-uniform guards only.
// arrs: [0]=e3 [1]=ne [2]=e1 [3]=e2 [4]=f3 [5]=nf [6]=f1 [7]=f2
// Grid: 2816 = 8 XCD * 16 graphs * 22 (11 tiles x 2 sets).
// ---------------------------------------------------------------------------
__global__ __launch_bounds__(256) void gather_all(
    const float* __restrict__ e, const float* __restrict__ f,
    const unsigned* __restrict__ efh,
    const float* __restrict__ Gd, const float* __restrict__ Bd,
    const float* __restrict__ Pd, const float* __restrict__ Qd,
    const float* __restrict__ w_ae, const float* __restrict__ w_af,
    const int* __restrict__ offs, const int2* __restrict__ pairs,
    unsigned* __restrict__ arrs, float* __restrict__ partials)
{
    int tid = threadIdx.x, lane = tid & 63, wv = tid >> 6;
    int bid = blockIdx.x;
    int xcd = bid & 7, loc = bid >> 3;          // loc 0..351
    int g    = xcd*16 + loc/22;
    int sub  = loc % 22;
    int set  = (sub < NTILE) ? 0 : 1;
    int tile = sub - set*NTILE;
    int r0   = tile*TROWS;
    int rlim = min(TROWS, N_NODES - r0);
    int mA = set ? 2 : 0, mB = set ? 3 : 1;

    const int*  poA = offs + (size_t)(mA*N_GRAPH + g)*OSTR;
    const int*  poB = offs + (size_t)(mB*N_GRAPH + g)*OSTR;
    const int2* ppA = pairs + (size_t)(mA*N_GRAPH + g)*PSTR;
    const int2* ppB = pairs + (size_t)(mB*N_GRAPH + g)*PSTR;

    float wa = w_ae[lane], wf = w_af[lane];
    float pa0 = 0.f, pa1 = 0.f, pa2 = 0.f, pa3 = 0.f;

    // preload first row's offsets
    int csA = 0, ctA = 0, csB = 0, ctB = 0;
    if (wv < rlim) {
        int r = r0 + wv;
        csA = __builtin_amdgcn_readfirstlane(poA[r]);
        ctA = __builtin_amdgcn_readfirstlane(poA[r+1]);
        csB = __builtin_amdgcn_readfirstlane(poB[r]);
        ctB = __builtin_amdgcn_readfirstlane(poB[r+1]);
    }

    for (int lr = wv; lr < rlim; lr += 4) {
        int r = r0 + lr;
        int node = g*N_NODES + r;

        // (a) prefetch next row's offsets (consumed next iteration)
        int nlr = lr + 4;
        int nr = r0 + ((nlr < rlim) ? nlr : lr);
        int nsA = __builtin_amdgcn_readfirstlane(poA[nr]);
        int ntA = __builtin_amdgcn_readfirstlane(poA[nr+1]);
        int nsB = __builtin_amdgcn_readfirstlane(poB[nr]);
        int ntB = __builtin_amdgcn_readfirstlane(poB[nr+1]);

        int sA = csA, tA = ctA, sB = csB, tB = ctB;
        int dA = tA - sA, dB = tB - sB;        // multiples of 4 (padded)
        int nmax = max(dA, dB);

        float aE = 0.f, aF = 0.f, bE = 0.f, bF = 0.f;

        // (b) pair double-buffer: preload chunk 0
        int2 qA[4], qB[4];
        if (0 < dA) {
            #pragma unroll
            for (int j = 0; j < 4; ++j) qA[j] = ppA[sA + j];
        }
        if (0 < dB) {
            #pragma unroll
            for (int j = 0; j < 4; ++j) qB[j] = ppB[sB + j];
        }

        for (int base = 0; base < nmax; base += 4) {
            bool hA = base < dA, hB = base < dB;       // wave-uniform
            unsigned uA[4], uB[4];
            // gathers for current chunk
            if (hA) {
                #pragma unroll
                for (int j = 0; j < 4; ++j) uA[j] = efh[((unsigned)qA[j].x << 6) + (unsigned)lane];
            }
            if (hB) {
                #pragma unroll
                for (int j = 0; j < 4; ++j) uB[j] = efh[((unsigned)qB[j].x << 6) + (unsigned)lane];
            }
            // preload next chunk's pairs (hidden under gather latency)
            int nb = base + 4;
            bool hA2 = nb < dA, hB2 = nb < dB;
            int2 q2A[4], q2B[4];
            if (hA2) {
                #pragma unroll
                for (int j = 0; j < 4; ++j) q2A[j] = ppA[sA + nb + j];
            }
            if (hB2) {
                #pragma unroll
                for (int j = 0; j < 4; ++j) q2B[j] = ppB[sB + nb + j];
            }
            // FMAs for current chunk (vals from current q, feats from gathers)
            if (hA) {
                #pragma unroll
                for (int j = 0; j < 4; ++j) {
                    float v = __int_as_float(qA[j].y);
                    aE = fmaf(v, __uint_as_float(uA[j] & 0xFFFF0000u), aE);
                    aF = fmaf(v, __uint_as_float(uA[j] << 16), aF);
                }
            }
            if (hB) {
                #pragma unroll
                for (int j = 0; j < 4; ++j) {
                    float v = __int_as_float(qB[j].y);
                    bE = fmaf(v, __uint_as_float(uB[j] & 0xFFFF0000u), bE);
                    bF = fmaf(v, __uint_as_float(uB[j] << 16), bF);
                }
            }
            // rotate buffers
            #pragma unroll
            for (int j = 0; j < 4; ++j) { qA[j] = q2A[j]; qB[j] = q2B[j]; }
        }

        size_t idx = (size_t)node*FDIM + lane;
        if (set == 0) {
            float ev = e[idx], fv = f[idx];
            float gd = Gd[node], bd = Bd[node], pd = Pd[node], qd = Qd[node];
            float e3v, nev, f3v, nfv;
            node_math1(ev, fv, gd, bd, pd, qd, aE, aF, bE, bF, e3v, nev, f3v, nfv);
            arrs[0*NF + idx] = pack_bf(e3v);
            arrs[1*NF + idx] = pack_bf(nev);
            arrs[4*NF + idx] = pack_bf(f3v);
            arrs[5*NF + idx] = pack_bf(nfv);
            pa0 += e3v*wa; pa1 += nev*wa; pa2 += f3v*wf; pa3 += nfv*wf;
        } else {
            arrs[2*NF + idx] = pack_bf(aE);   // e1
            arrs[3*NF + idx] = pack_bf(bE);   // e2
            arrs[6*NF + idx] = pack_bf(aF);   // f1
            arrs[7*NF + idx] = pack_bf(bF);   // f2
            pa0 += aE*wa; pa1 += bE*wa; pa2 += aF*wf; pa3 += bF*wf;
        }

        csA = nsA; ctA = ntA; csB = nsB; ctB = ntB;
    }

    __shared__ float sred[4];
    if (tid < 4) sred[tid] = 0.f;
    __syncthreads();
    #pragma unroll
    for (int off = 32; off > 0; off >>= 1) {
        pa0 += __shfl_down(pa0, off); pa1 += __shfl_down(pa1, off);
        pa2 += __shfl_down(pa2, off); pa3 += __shfl_down(pa3, off);
    }
    if (lane == 0) {
        atomicAdd(&sred[0], pa0); atomicAdd(&sred[1], pa1);
        atomicAdd(&sred[2], pa2); atomicAdd(&sred[3], pa3);
    }
    __syncthreads();
    if (tid == 0) {
        float* pt = partials + ((size_t)g*NTILE + tile)*8;
        if (set == 0) { pt[0] = sred[0]; pt[1] = sred[1]; pt[4] = sred[2]; pt[5] = sred[3]; }
        else          { pt[2] = sred[0]; pt[3] = sred[1]; pt[6] = sred[2]; pt[7] = sred[3]; }
    }
}

// ---------------------------------------------------------------------------
// Kernel 3: finalize attention weights (normalized)
// ---------------------------------------------------------------------------
__global__ void attn_final(const float* __restrict__ partials,
                           const float* __restrict__ b_ae, const float* __restrict__ b_af,
                           float* __restrict__ att)
{
    int g = threadIdx.x;
    if (g >= N_GRAPH) return;
    float s[8];
    #pragma unroll
    for (int j = 0; j < 8; ++j) {
        float t = 0.f;
        for (int q = 0; q < NTILE; ++q) t += partials[((size_t)g*NTILE + q)*8 + j];
        s[j] = t;
    }
    float ae[4], af[4], se = 1e-4f, sf = 1e-4f;
    float bae = b_ae[0], baf = b_af[0];
    #pragma unroll
    for (int j = 0; j < 4; ++j) {
        float x = s[j]*(1.0f/N_NODES) + bae;
        ae[j] = 1.0f/(1.0f + expf(-x)); se += ae[j];
        float y = s[4+j]*(1.0f/N_NODES) + baf;
        af[j] = 1.0f/(1.0f + expf(-y)); sf += af[j];
    }
    #pragma unroll
    for (int j = 0; j < 4; ++j) {
        att[g*8 + j]     = ae[j]/se;
        att[g*8 + 4 + j] = af[j]/sf;
    }
}

// ---------------------------------------------------------------------------
// Kernel 4: MFMA epilogue (round-1/6 proven). Stage packed-bf16 uints into
// LDS in fragment order (10 segs: e3,ne,e1,e2,e | f3,nf,f1,f2,f), unpack
// hi/lo with shifts, 5 per-segment accumulators, att folded post-MFMA,
// tanh + store. LDS slot layout: [seg*8+(feat>>3)][node 0..15][8], stride 132.
// ---------------------------------------------------------------------------
__global__ __launch_bounds__(256) void final_fused(
    const float* __restrict__ e, const float* __restrict__ f,
    const unsigned* __restrict__ arrs, const float* __restrict__ att,
    const unsigned short* __restrict__ Wb1h, const unsigned short* __restrict__ Wb1l,
    const unsigned short* __restrict__ Wb2h, const unsigned short* __restrict__ Wb2l,
    const float* __restrict__ bv1, const float* __restrict__ bv2,
    float* __restrict__ out)
{
    __shared__ __align__(16) unsigned sfrag[80*132];

    int tid = threadIdx.x, lane = tid & 63, chunk = tid >> 6;
    int node0 = blockIdx.x * 16;
    int sl = lane >> 3, jj = lane & 7;

    #pragma unroll
    for (int round = 0; round < 4; ++round) {
        int ni = round*4 + chunk;
        size_t idx = (size_t)(node0 + ni)*FDIM + lane;
        #pragma unroll
        for (int seg = 0; seg < 10; ++seg) {
            unsigned u;
            if (seg == 4)      u = pack_bf(e[idx]);
            else if (seg == 9) u = pack_bf(f[idx]);
            else {
                int a = (seg < 4) ? seg : seg - 1;   // segs 0..3 -> arrs0..3; 5..8 -> arrs4..7
                u = arrs[(size_t)a*NF + idx];
            }
            sfrag[(seg*8 + sl)*132 + ni*8 + jj] = u;
        }
    }
    __syncthreads();

    int m16 = lane & 15, quad = lane >> 4;
    float4v acce[5], accf[5];
    #pragma unroll
    for (int s = 0; s < 5; ++s) {
        acce[s] = (float4v){0.f,0.f,0.f,0.f};
        accf[s] = (float4v){0.f,0.f,0.f,0.f};
    }

    #pragma unroll
    for (int seg = 0; seg < 5; ++seg) {
        #pragma unroll
        for (int ks2 = 0; ks2 < 2; ++ks2) {
            int ks = seg*2 + ks2;
            size_t boff = (size_t)((ks*4 + chunk)*64 + lane)*8;
            // e-side
            {
                const unsigned* pa = &sfrag[(seg*8 + ks2*4 + quad)*132 + m16*8];
                uint4 ua = *(const uint4*)pa;
                uint4 ub = *(const uint4*)(pa + 4);
                unsigned uu[8] = {ua.x,ua.y,ua.z,ua.w,ub.x,ub.y,ub.z,ub.w};
                short8 ah, al;
                #pragma unroll
                for (int j = 0; j < 8; ++j) {
                    ah[j] = (short)(uu[j] >> 16);
                    al[j] = (short)(uu[j] & 0xFFFFu);
                }
                short8 bh = *(const short8*)(Wb1h + boff);
                short8 bl = *(const short8*)(Wb1l + boff);
                acce[seg] = __builtin_amdgcn_mfma_f32_16x16x32_bf16(ah, bh, acce[seg], 0, 0, 0);
                acce[seg] = __builtin_amdgcn_mfma_f32_16x16x32_bf16(al, bh, acce[seg], 0, 0, 0);
                acce[seg] = __builtin_amdgcn_mfma_f32_16x16x32_bf16(ah, bl, acce[seg], 0, 0, 0);
            }
            // f-side
            {
                const unsigned* pa = &sfrag[((seg+5)*8 + ks2*4 + quad)*132 + m16*8];
                uint4 ua = *(const uint4*)pa;
                uint4 ub = *(const uint4*)(pa + 4);
                unsigned uu[8] = {ua.x,ua.y,ua.z,ua.w,ub.x,ub.y,ub.z,ub.w};
                short8 ch, cl;
                #pragma unroll
                for (int j = 0; j < 8; ++j) {
                    ch[j] = (short)(uu[j] >> 16);
                    cl[j] = (short)(uu[j] & 0xFFFFu);
                }
                short8 bh = *(const short8*)(Wb2h + boff);
                short8 bl = *(const short8*)(Wb2l + boff);
                accf[seg] = __builtin_amdgcn_mfma_f32_16x16x32_bf16(ch, bh, accf[seg], 0, 0, 0);
                accf[seg] = __builtin_amdgcn_mfma_f32_16x16x32_bf16(cl, bh, accf[seg], 0, 0, 0);
                accf[seg] = __builtin_amdgcn_mfma_f32_16x16x32_bf16(ch, bl, accf[seg], 0, 0, 0);
            }
        }
    }

    int o = chunk*16 + m16;
    float be = bv1[o], bf = bv2[o];
    #pragma unroll
    for (int reg = 0; reg < 4; ++reg) {
        int node = node0 + quad*4 + reg;
        int g = node / N_NODES;
        float se2 = acce[4][reg];
        float sf2 = accf[4][reg];
        #pragma unroll
        for (int b = 0; b < 4; ++b) {
            se2 = fmaf(att[g*8 + b],     acce[b][reg], se2);
            sf2 = fmaf(att[g*8 + 4 + b], accf[b][reg], sf2);
        }
        out[(size_t)node*FDIM + o]      = tanhf(se2 + be);
        out[NF + (size_t)node*FDIM + o] = tanhf(sf2 + bf);
    }
}

// ---------------------------------------------------------------------------
extern "C" void kernel_launch(void* const* d_in, const int* in_sizes, int n_in,
                              void* d_out, int out_size, void* d_ws, size_t ws_size,
                              hipStream_t stream) {
    (void)in_sizes; (void)n_in; (void)out_size; (void)ws_size;
    const float* e     = (const float*)d_in[0];
    const float* f     = (const float*)d_in[1];
    const int*   rowsG = (const int*)d_in[2];
    const int*   colsG = (const int*)d_in[3];
    const float* valsG = (const float*)d_in[4];
    const int*   rowsB = (const int*)d_in[5];
    const int*   colsB = (const int*)d_in[6];
    const float* valsB = (const float*)d_in[7];
    const int*   rows1 = (const int*)d_in[8];
    const int*   cols1 = (const int*)d_in[9];
    const float* vals1 = (const float*)d_in[10];
    const int*   rows2 = (const int*)d_in[11];
    const int*   cols2 = (const int*)d_in[12];
    const float* vals2 = (const float*)d_in[13];
    const float* G_d   = (const float*)d_in[14];
    const float* B_d   = (const float*)d_in[15];
    const float* Pd    = (const float*)d_in[16];
    const float* Qd    = (const float*)d_in[17];
    const float* W1    = (const float*)d_in[18];
    const float* b1    = (const float*)d_in[19];
    const float* W2    = (const float*)d_in[20];
    const float* b2    = (const float*)d_in[21];
    const float* w_ae  = (const float*)d_in[22];
    const float* b_ae  = (const float*)d_in[23];
    const float* w_af  = (const float*)d_in[24];
    const float* b_af  = (const float*)d_in[25];

    unsigned* arrs  = (unsigned*)d_ws;               // 8*NF uints (packed bf16 h|l)
    float* partials = (float*)(arrs + 8*NF);         // 128*11*8 = 11264
    float* att      = partials + 11264;              // 1024 (normalized weights)
    unsigned short* Wb1h = (unsigned short*)(att + 1024);  // 20480 shorts each
    unsigned short* Wb1l = Wb1h + 20480;
    unsigned short* Wb2h = Wb1l + 20480;
    unsigned short* Wb2l = Wb2h + 20480;
    int*   offs     = (int*)(Wb2l + 20480);          // 512*OSTR ints
    int2*  pairs    = (int2*)(offs + 512*OSTR);      // 512*PSTR int2 (padded CSR)
    unsigned* efh   = (unsigned*)(pairs + (size_t)512*PSTR);  // NF uints (bf16 e|f pairs)

    prep_pack<<<dim3(80 + PACKB), dim3(256), 0, stream>>>(
        W1, W2, e, f, Wb1h, Wb1l, Wb2h, Wb2l, efh);

    csr_build<<<dim3(512), dim3(1024), 0, stream>>>(
        rowsG, colsG, valsG, rowsB, colsB, valsB,
        rows1, cols1, vals1, rows2, cols2, vals2, offs, pairs);

    gather_all<<<dim3(2816), dim3(256), 0, stream>>>(
        e, f, efh, G_d, B_d, Pd, Qd, w_ae, w_af, offs, pairs, arrs, partials);

    attn_final<<<dim3(1), dim3(128), 0, stream>>>(partials, b_ae, b_af, att);

    final_fused<<<dim3(NTOT/16), dim3(256), 0, stream>>>(
        e, f, arrs, att, Wb1h, Wb1l, Wb2h, Wb2l, b1, b2, (float*)d_out);
}